// Round 1
// baseline (82.866 us; speedup 1.0000x reference)
//
#include <hip/hip_runtime.h>
#include <math.h>

// HybridQuanvolutionEstimator — analytic collapse of the quantum circuit.
//
// feats[b,c,h,w] = conv2x2 stride2 (x) + bias              (NCHW)
// flat[b,n] = feats channel-major; patch p angles = flat[b, 4p..4p+3], c = p/49
// z0 = cos(a0+th0); z1 = cos(th1)*cos(a1); z2 = cos(a2); z3 = cos(a3+th3)
// qf[b, 4p..4p+3] = [z0, z0*z1, z0*z1*z2, z1*z2*z3]
// logits = qf @ lin_w.T + lin_b ; out = log_softmax(logits)
//
// One block per batch element: stage x[b] in LDS, each of 196 threads handles
// one patch (4 conv outputs + 4 cos + 10 float4 dots), reduce 10 logits.

#define NB 4096
#define NPATCH 196

__global__ __launch_bounds__(256) void hqe_kernel(
    const float* __restrict__ x,       // [B, 784]
    const float* __restrict__ conv_w,  // [4,1,2,2] = 16
    const float* __restrict__ conv_b,  // [4]
    const float* __restrict__ q_theta, // [4]
    const float* __restrict__ lin_w,   // [10, 784]
    const float* __restrict__ lin_b,   // [10]
    float* __restrict__ out)           // [B, 10]
{
    __shared__ __align__(16) float xs[784];
    __shared__ float red[4][10];
    __shared__ float logits_s[10];

    const int b = blockIdx.x;
    const int t = threadIdx.x;

    // stage x[b] (28x28) into LDS: 196 float4 coalesced loads
    if (t < 196) {
        ((float4*)xs)[t] = ((const float4*)(x + b * 784))[t];
    }

    // uniform small params (L1/sgpr cached)
    const float th0 = q_theta[0];
    const float ct1 = cosf(q_theta[1]);
    const float th3 = q_theta[3];

    __syncthreads();

    float partial[10];
#pragma unroll
    for (int o = 0; o < 10; ++o) partial[o] = 0.0f;

    if (t < NPATCH) {
        const int p = t;
        const int c = p / 49;                 // channel constant across k (196 = 4*49)
        const float4 cw = ((const float4*)conv_w)[c];
        const float cb = conv_b[c];
        const int rbase = 4 * p - 196 * c;    // flat index within channel

        float a[4];
#pragma unroll
        for (int k = 0; k < 4; ++k) {
            const int r = rbase + k;
            const int h = r / 14;
            const int w = r - 14 * h;
            const float* xp = xs + (2 * h) * 28 + 2 * w;
            a[k] = cb + xp[0] * cw.x + xp[1] * cw.y + xp[28] * cw.z + xp[29] * cw.w;
        }

        const float z0 = cosf(a[0] + th0);
        const float z1 = ct1 * cosf(a[1]);
        const float z2 = cosf(a[2]);
        const float z3 = cosf(a[3] + th3);
        const float f0 = z0;
        const float f1 = z0 * z1;
        const float f2 = f1 * z2;
        const float f3 = z1 * z2 * z3;

        const float4* w4 = (const float4*)lin_w;  // [10*196] float4, w4[o*196+p] aligned
#pragma unroll
        for (int o = 0; o < 10; ++o) {
            const float4 w = w4[o * 196 + p];
            partial[o] = f0 * w.x + f1 * w.y + f2 * w.z + f3 * w.w;
        }
    }

    // wave (64-lane) shuffle reduction of the 10 partial logits
#pragma unroll
    for (int o = 0; o < 10; ++o) {
        float v = partial[o];
#pragma unroll
        for (int off = 32; off > 0; off >>= 1)
            v += __shfl_down(v, off, 64);
        partial[o] = v;
    }
    const int wave = t >> 6;
    const int lane = t & 63;
    if (lane == 0) {
#pragma unroll
        for (int o = 0; o < 10; ++o) red[wave][o] = partial[o];
    }
    __syncthreads();

    if (t < 10) {
        logits_s[t] = red[0][t] + red[1][t] + red[2][t] + red[3][t] + lin_b[t];
    }
    __syncthreads();

    if (t < 10) {
        float m = -INFINITY;
#pragma unroll
        for (int o = 0; o < 10; ++o) m = fmaxf(m, logits_s[o]);
        float s = 0.0f;
#pragma unroll
        for (int o = 0; o < 10; ++o) s += expf(logits_s[o] - m);
        out[b * 10 + t] = logits_s[t] - m - logf(s);
    }
}

extern "C" void kernel_launch(void* const* d_in, const int* in_sizes, int n_in,
                              void* d_out, int out_size, void* d_ws, size_t ws_size,
                              hipStream_t stream) {
    const float* x       = (const float*)d_in[0];
    const float* conv_w  = (const float*)d_in[1];
    const float* conv_b  = (const float*)d_in[2];
    const float* q_theta = (const float*)d_in[3];
    const float* lin_w   = (const float*)d_in[4];
    const float* lin_b   = (const float*)d_in[5];
    float* out = (float*)d_out;

    hqe_kernel<<<dim3(NB), dim3(256), 0, stream>>>(x, conv_w, conv_b, q_theta,
                                                   lin_w, lin_b, out);
}

// Round 2
// 78.412 us; speedup vs baseline: 1.0568x; 1.0568x over previous
//
#include <hip/hip_runtime.h>
#include <math.h>

// HybridQuanvolutionEstimator — analytic collapse of the quantum circuit.
//
// z0 = cos(a0+th0); z1 = cos(th1)*cos(a1); z2 = cos(a2); z3 = cos(a3+th3)
// qf[b, 4p..4p+3] = [z0, z0*z1, z0*z1*z2, z1*z2*z3]
// logits = qf @ lin_w.T + lin_b ; out = log_softmax(logits)
//
// R2 changes vs R1:
//  - __cosf/__expf/__logf (native v_cos/v_exp/v_log) instead of precise libm
//    (args bounded |a| <~ 12; abs err ~1e-5 vs 7e-2 threshold)
//  - features round-trip through LDS; each wave owns whole outputs
//    (wave w -> outputs w, w+4, w+8), so the 64-lane tree reduction runs
//    10x total per block instead of 10x per wave: 240 -> 60 DS shuffles/b.

#define NB 4096

__global__ __launch_bounds__(256) void hqe_kernel(
    const float* __restrict__ x,       // [B, 784]
    const float* __restrict__ conv_w,  // [4,1,2,2]
    const float* __restrict__ conv_b,  // [4]
    const float* __restrict__ q_theta, // [4]
    const float* __restrict__ lin_w,   // [10, 784]
    const float* __restrict__ lin_b,   // [10]
    float* __restrict__ out)           // [B, 10]
{
    __shared__ __align__(16) float xs[784];
    __shared__ __align__(16) float qf[784];
    __shared__ float logits_s[10];

    const int b = blockIdx.x;
    const int t = threadIdx.x;
    const int wave = t >> 6;
    const int lane = t & 63;

    // stage x[b] into LDS (196 coalesced float4); init logits with bias
    if (t < 196) {
        ((float4*)xs)[t] = ((const float4*)(x + b * 784))[t];
    } else if (t < 206) {
        logits_s[t - 196] = lin_b[t - 196];
    }

    const float th0 = q_theta[0];
    const float ct1 = __cosf(q_theta[1]);
    const float th3 = q_theta[3];

    __syncthreads();

    // phase 1: thread t = patch t computes its 4 features -> LDS
    if (t < 196) {
        const int c = t / 49;               // channel (196 = 4*49)
        const int rbase = 4 * t - 196 * c;  // flat spatial index in channel
        const float4 cw = ((const float4*)conv_w)[c];
        const float cb = conv_b[c];
        float a[4];
#pragma unroll
        for (int k = 0; k < 4; ++k) {
            const int s = rbase + k;
            const int h = s / 14;
            const int w = s - 14 * h;
            const float* xp = xs + 56 * h + 2 * w;
            a[k] = cb + xp[0] * cw.x + xp[1] * cw.y + xp[28] * cw.z + xp[29] * cw.w;
        }
        const float z0 = __cosf(a[0] + th0);
        const float z1 = ct1 * __cosf(a[1]);
        const float z2 = __cosf(a[2]);
        const float z3 = __cosf(a[3] + th3);
        const float f1 = z0 * z1;
        const float f2 = f1 * z2;
        const float f3 = z1 * z2 * z3;
        ((float4*)qf)[t] = make_float4(z0, f1, f2, f3);
    }

    __syncthreads();

    // phase 2: wave w computes logits w, w+4, w+8 as 64-lane dot products.
    // qf fragments loaded once per wave, reused across its outputs.
    const float4* q4 = (const float4*)qf;
    const float4 q0 = q4[lane];
    const float4 q1 = q4[64 + lane];
    const float4 q2 = q4[128 + lane];
    float4 q3 = make_float4(0.f, 0.f, 0.f, 0.f);
    if (lane < 4) q3 = q4[192 + lane];

    for (int o = wave; o < 10; o += 4) {
        const float4* wv = (const float4*)(lin_w + o * 784);
        const float4 w0 = wv[lane];
        const float4 w1 = wv[64 + lane];
        const float4 w2 = wv[128 + lane];
        float s = q0.x * w0.x + q0.y * w0.y + q0.z * w0.z + q0.w * w0.w;
        s += q1.x * w1.x + q1.y * w1.y + q1.z * w1.z + q1.w * w1.w;
        s += q2.x * w2.x + q2.y * w2.y + q2.z * w2.z + q2.w * w2.w;
        if (lane < 4) {
            const float4 w3 = wv[192 + lane];
            s += q3.x * w3.x + q3.y * w3.y + q3.z * w3.z + q3.w * w3.w;
        }
#pragma unroll
        for (int off = 32; off > 0; off >>= 1)
            s += __shfl_down(s, off, 64);
        if (lane == 0) logits_s[o] += s;   // each o owned by exactly one wave
    }

    __syncthreads();

    // log-softmax over the 10 logits
    if (t < 10) {
        float m = -INFINITY;
#pragma unroll
        for (int j = 0; j < 10; ++j) m = fmaxf(m, logits_s[j]);
        float sum = 0.0f;
#pragma unroll
        for (int j = 0; j < 10; ++j) sum += __expf(logits_s[j] - m);
        out[b * 10 + t] = logits_s[t] - m - __logf(sum);
    }
}

extern "C" void kernel_launch(void* const* d_in, const int* in_sizes, int n_in,
                              void* d_out, int out_size, void* d_ws, size_t ws_size,
                              hipStream_t stream) {
    const float* x       = (const float*)d_in[0];
    const float* conv_w  = (const float*)d_in[1];
    const float* conv_b  = (const float*)d_in[2];
    const float* q_theta = (const float*)d_in[3];
    const float* lin_w   = (const float*)d_in[4];
    const float* lin_b   = (const float*)d_in[5];
    float* out = (float*)d_out;

    hqe_kernel<<<dim3(NB), dim3(256), 0, stream>>>(x, conv_w, conv_b, q_theta,
                                                   lin_w, lin_b, out);
}